// Round 8
// baseline (350.805 us; speedup 1.0000x reference)
//
#include <hip/hip_runtime.h>
#include <hip/hip_bf16.h>
#include <math.h>

// B=8, S=1024, D=1024, H=16, DH=64
typedef __attribute__((ext_vector_type(8))) short s16x8;
typedef __attribute__((ext_vector_type(4))) unsigned short u16x4;
typedef __attribute__((ext_vector_type(4))) float f32x4;

static __device__ __forceinline__ unsigned short f2bf(float f) {
  unsigned int u = __builtin_bit_cast(unsigned int, f);
  u += 0x7fffu + ((u >> 16) & 1u);
  return (unsigned short)(u >> 16);
}

// async global->LDS, 16B per lane; LDS dest = wave-uniform base + lane*16 (m97 pattern)
typedef const __attribute__((address_space(1))) unsigned int* gas1_t;
typedef __attribute__((address_space(3))) unsigned int* las3_t;
static __device__ __forceinline__ void gload_lds16(const unsigned short* g, unsigned short* l) {
  __builtin_amdgcn_global_load_lds((gas1_t)g, (las3_t)l, 16, 0, 0);
}

// ---------------- X fp32 -> bf16 ----------------
__global__ __launch_bounds__(256) void conv_x_kernel(const float* __restrict__ x,
                                                     unsigned short* __restrict__ xb) {
  int i = blockIdx.x * 256 + threadIdx.x;  // grid sized exactly: 8192*1024/4 threads
  const float4 v = ((const float4*)x)[i];
  u16x4 o = {f2bf(v.x), f2bf(v.y), f2bf(v.z), f2bf(v.w)};
  ((u16x4*)xb)[i] = o;
}

// ---------------- pack W^T (bf16): rows [0,1024)=Wq^T, [1024,2048)=Wk^T,
// [2048,3072)=Wv^T, [3072,4096)=Wo^T.  Wt[n][k] = W[k][n] ----------------
__global__ void pack_w_kernel(const float* __restrict__ Wq, const float* __restrict__ Wk,
                              const float* __restrict__ Wv, const float* __restrict__ Wo,
                              unsigned short* __restrict__ Wt) {
  __shared__ float t[32][33];
  const int z = blockIdx.z;
  const float* W = z == 0 ? Wq : (z == 1 ? Wk : (z == 2 ? Wv : Wo));
  const int n0 = blockIdx.x * 32, k0 = blockIdx.y * 32;
  const int tx = threadIdx.x, ty = threadIdx.y;  // 32 x 8
#pragma unroll
  for (int i = 0; i < 4; ++i)
    t[ty + i * 8][tx] = W[(k0 + ty + i * 8) * 1024 + n0 + tx];
  __syncthreads();
#pragma unroll
  for (int i = 0; i < 4; ++i)
    Wt[(z * 1024 + n0 + ty + i * 8) * 1024 + k0 + tx] = f2bf(t[tx][ty + i * 8]);
}

// ---------------- QKV GEMM: [8192x1024] @ [1024x3072] + bias, scatter to
// Q [B][H][S][DH] (scaled log2e/8), K [B][H][S][DH], V^T [B][H][DH][S] ----------------
// 128x128 tile, BK=32. A staged via global_load_lds (dbuf); B (L2-hot weights) read
// DIRECTLY global->VGPR, software-pipelined one iteration ahead. Halves LDS traffic.
__global__ __launch_bounds__(256, 4) void gemm_qkv_kernel(
    const unsigned short* __restrict__ A, const unsigned short* __restrict__ Wt,
    const float* __restrict__ bq, const float* __restrict__ bk, const float* __restrict__ bv,
    unsigned short* __restrict__ Qb, unsigned short* __restrict__ Kb,
    unsigned short* __restrict__ VT) {
  __shared__ unsigned short As[2][128 * 32];
  const int tid = threadIdx.x;
  const int l = tid & 63, w = tid >> 6;
  const int wr = w >> 1, wc = w & 1;
  const int lq = l & 15, lg = l >> 4;
  const int m0 = blockIdx.y * 128;
  const int n0 = blockIdx.x * 128;  // 24 blocks -> [0,3072)
  const int sr = w * 32 + (l >> 2);   // staging row (call 0); +16 for call 1
  const int sc = (l & 3) * 8;         // staging col (elements)

  f32x4 acc[4][4] = {};

  // per-lane B fragment base: row = n0 + wc*64 + lq (+n*16), col = lg*8 (+kt*32)
  const unsigned short* Bp = Wt + (size_t)(n0 + wc * 64 + lq) * 1024 + lg * 8;

#define STAGE_A(KT, BUF)                                                        \
  {                                                                             \
    const int kc_ = (KT) * 32 + sc;                                             \
    gload_lds16(&A[(m0 + sr) * 1024 + kc_],      &As[BUF][(w * 2 + 0) * 512]);  \
    gload_lds16(&A[(m0 + sr + 16) * 1024 + kc_], &As[BUF][(w * 2 + 1) * 512]);  \
  }

  s16x8 bc[4], bn[4];
#pragma unroll
  for (int n = 0; n < 4; ++n) bc[n] = *(const s16x8*)&Bp[n * 16 * 1024];
  STAGE_A(0, 0);
  __syncthreads();  // tile 0 staged

  int cur = 0;
  for (int kt = 0; kt < 32; ++kt) {
    if (kt + 1 < 32) {
      STAGE_A(kt + 1, cur ^ 1);  // issue-only; drains at end-of-iter barrier
      const int kn = (kt + 1) * 32;
#pragma unroll
      for (int n = 0; n < 4; ++n) bn[n] = *(const s16x8*)&Bp[n * 16 * 1024 + kn];
    }
    s16x8 af[4];
#pragma unroll
    for (int m = 0; m < 4; ++m)
      af[m] = *(const s16x8*)&As[cur][(wr * 64 + m * 16 + lq) * 32 + lg * 8];
#pragma unroll
    for (int m = 0; m < 4; ++m)
#pragma unroll
      for (int n = 0; n < 4; ++n)
        acc[m][n] = __builtin_amdgcn_mfma_f32_16x16x32_bf16(af[m], bc[n], acc[m][n], 0, 0, 0);
    __syncthreads();  // A prefetch complete + all A reads done -> safe flip
    cur ^= 1;
#pragma unroll
    for (int n = 0; n < 4; ++n) bc[n] = bn[n];
  }
#undef STAGE_A

  const int sec = n0 >> 10;  // uniform per block: 0=Q 1=K 2=V
  const float* bias = sec == 0 ? bq : (sec == 1 ? bk : bv);
#pragma unroll
  for (int nf = 0; nf < 4; ++nf) {
    const int ng = n0 + wc * 64 + nf * 16 + lq;
    const int c = ng & 1023;
    const int h = c >> 6, dh = c & 63;
    const float bsv = bias[c];
#pragma unroll
    for (int mf = 0; mf < 4; ++mf) {
      const int mg = m0 + wr * 64 + mf * 16 + lg * 4;
      const int b = mg >> 10, s = mg & 1023;
#pragma unroll
      for (int r = 0; r < 4; ++r) {
        const float v = acc[mf][nf][r] + bsv;
        if (sec == 0)
          Qb[((b * 16 + h) * 1024 + s + r) * 64 + dh] =
              f2bf(v * (0.125f * 1.44269504088896f));  // fold 1/sqrt(64) and log2(e): softmax in exp2 domain
        else if (sec == 1)
          Kb[((b * 16 + h) * 1024 + s + r) * 64 + dh] = f2bf(v);
        else
          VT[((b * 16 + h) * 64 + dh) * 1024 + s + r] = f2bf(v);
      }
    }
  }
}

// ---------------- flash attention: 1 block = 64 q-rows of one (b,h); 4 waves x 16 rows.
// swapped QK^T (mfma(K,Q)) -> lane owns one q-col; online softmax (exp2 domain);
// PV via ctx^T = V^T @ P^T. K/V tiles staged block-wide in double-buffered LDS via
// global_load_lds (2-phase: issue STAGE(t+1) before compute(t), one barrier per tile).
// XOR chunk-swizzle (chunk ^= row&7) applied on the GLOBAL source + on ds_read addr,
// LDS write stays linear (rule #21): balanced 32B/bank reads.
__global__ __launch_bounds__(256, 3) void attn_kernel(
    const unsigned short* __restrict__ Qb, const unsigned short* __restrict__ Kb,
    const unsigned short* __restrict__ VT, const int* __restrict__ lens,
    unsigned short* __restrict__ ctx) {
  __shared__ unsigned short Ks[2][64 * 64];  // [buf][row*64 + chunk*8], chunk pre-swizzled
  __shared__ unsigned short Vs[2][64 * 64];
  __shared__ unsigned short Pw[4][16][72];   // per-wave P[q][k] tile, padded
  const int tid = threadIdx.x;
  const int l = tid & 63, w = tid >> 6;
  const int lq = l & 15, lg = l >> 4;
  const int l8r = l >> 3;      // staging: row within 8-row group
  const int swz = (l & 7) ^ (l8r & 7);  // source chunk for linear LDS slot
  const int qt = blockIdx.x & 15;
  const int bh = blockIdx.x >> 4;
  const int b = bh >> 4, h = bh & 15;
  const int len = lens[b];

  const unsigned short* Qp = Qb + bh * 1024 * 64;
  const unsigned short* Kp = Kb + bh * 1024 * 64;
  const unsigned short* Vp = VT + bh * 64 * 1024;

  const int qrow = qt * 64 + w * 16 + lq;
  s16x8 qf[2];
  qf[0] = *(const s16x8*)&Qp[qrow * 64 + lg * 8];
  qf[1] = *(const s16x8*)&Qp[qrow * 64 + 32 + lg * 8];

  float mrun = -INFINITY, lrun = 0.f;
  f32x4 cacc[4] = {};

  const int nkt = (len + 63) >> 6;

#define STAGE_KV(KT, BUF)                                                                     \
  {                                                                                           \
    const int kb_ = (KT) * 64;                                                                \
    gload_lds16(&Kp[(kb_ + w * 16 + l8r) * 64 + swz * 8],      &Ks[BUF][(w * 16) * 64]);      \
    gload_lds16(&Kp[(kb_ + w * 16 + 8 + l8r) * 64 + swz * 8],  &Ks[BUF][(w * 16 + 8) * 64]);  \
    gload_lds16(&Vp[(w * 16 + l8r) * 1024 + kb_ + swz * 8],     &Vs[BUF][(w * 16) * 64]);     \
    gload_lds16(&Vp[(w * 16 + 8 + l8r) * 1024 + kb_ + swz * 8], &Vs[BUF][(w * 16 + 8) * 64]); \
  }

  STAGE_KV(0, 0);
  __syncthreads();  // tile 0 staged

  int cur = 0;
  for (int kt = 0; kt < nkt; ++kt) {
    if (kt + 1 < nkt) STAGE_KV(kt + 1, cur ^ 1);  // issue-only; drained at end-of-iter barrier
    const int kbase = kt * 64;
    // scores^T tile [64 k][16 q] from LDS (swizzled read)
    f32x4 sacc[4] = {};
#pragma unroll
    for (int kk = 0; kk < 2; ++kk) {
#pragma unroll
      for (int n = 0; n < 4; ++n) {
        s16x8 kf = *(const s16x8*)&Ks[cur][(n * 16 + lq) * 64 + (((kk * 4 + lg) ^ (lq & 7)) << 3)];
        sacc[n] = __builtin_amdgcn_mfma_f32_16x16x32_bf16(kf, qf[kk], sacc[n], 0, 0, 0);
      }
    }
    // mask + tile max (per q-col: 16 lane-local + xor16 + xor32)
    float sv[4][4];
    float tmax = -INFINITY;
#pragma unroll
    for (int n = 0; n < 4; ++n)
#pragma unroll
      for (int r = 0; r < 4; ++r) {
        const int krow = kbase + n * 16 + lg * 4 + r;
        const float s = (krow < len) ? sacc[n][r] : -INFINITY;
        sv[n][r] = s;
        tmax = fmaxf(tmax, s);
      }
    tmax = fmaxf(tmax, __shfl_xor(tmax, 16));
    tmax = fmaxf(tmax, __shfl_xor(tmax, 32));
    const float mnew = fmaxf(mrun, tmax);
    const float corr = exp2f(mrun - mnew);  // exp2 domain (log2e folded into Q); first tile: 0
    float psum = 0.f;
#pragma unroll
    for (int n = 0; n < 4; ++n) {
      u16x4 pp;
#pragma unroll
      for (int r = 0; r < 4; ++r) {
        const float p = exp2f(sv[n][r] - mnew);  // masked -> exp2(-inf)=0
        psum += p;
        pp[r] = f2bf(p);
      }
      *(u16x4*)&Pw[w][lq][n * 16 + lg * 4] = pp;
    }
    psum += __shfl_xor(psum, 16);
    psum += __shfl_xor(psum, 32);
    lrun = lrun * corr + psum;
    mrun = mnew;
#pragma unroll
    for (int d = 0; d < 4; ++d) cacc[d] *= corr;
    asm volatile("s_waitcnt lgkmcnt(0)" ::: "memory");  // P writes visible to wave's reads
    // ctx^T += V^T @ P^T  (V from LDS, swizzled read)
#pragma unroll
    for (int kk = 0; kk < 2; ++kk) {
      s16x8 pf = *(const s16x8*)&Pw[w][lq][kk * 32 + lg * 8];
#pragma unroll
      for (int d = 0; d < 4; ++d) {
        s16x8 vf = *(const s16x8*)&Vs[cur][(d * 16 + lq) * 64 + (((kk * 4 + lg) ^ (lq & 7)) << 3)];
        cacc[d] = __builtin_amdgcn_mfma_f32_16x16x32_bf16(vf, pf, cacc[d], 0, 0, 0);
      }
    }
    __syncthreads();  // drains vmcnt (prefetch t+1 done) + lgkm; buffers safe to flip
    cur ^= 1;
  }
#undef STAGE_KV

  const float inv = 1.f / lrun;
  unsigned short* cp = ctx + (b * 1024 + qt * 64 + w * 16 + lq) * 1024 + h * 64;
#pragma unroll
  for (int d = 0; d < 4; ++d) {
    u16x4 o;
#pragma unroll
    for (int r = 0; r < 4; ++r) o[r] = f2bf(cacc[d][r] * inv);
    *(u16x4*)&cp[d * 16 + lg * 4] = o;
  }
}

// ---------------- O-proj GEMM: ctx[8192x1024] @ Wo + bo -> fp32 hidden (d_out) ----------------
// same A-staged / B-direct structure as gemm_qkv.
__global__ __launch_bounds__(256, 4) void gemm_o_kernel(const unsigned short* __restrict__ A,
                                                        const unsigned short* __restrict__ Wt,
                                                        const float* __restrict__ bo,
                                                        float* __restrict__ out) {
  __shared__ unsigned short As[2][128 * 32];
  const int tid = threadIdx.x;
  const int l = tid & 63, w = tid >> 6;
  const int wr = w >> 1, wc = w & 1;
  const int lq = l & 15, lg = l >> 4;
  const int m0 = blockIdx.y * 128;
  const int n0 = blockIdx.x * 128;
  const int sr = w * 32 + (l >> 2);
  const int sc = (l & 3) * 8;

  f32x4 acc[4][4] = {};
  const unsigned short* Bp = Wt + (size_t)(n0 + wc * 64 + lq) * 1024 + lg * 8;

#define STAGE_A(KT, BUF)                                                        \
  {                                                                             \
    const int kc_ = (KT) * 32 + sc;                                             \
    gload_lds16(&A[(m0 + sr) * 1024 + kc_],      &As[BUF][(w * 2 + 0) * 512]);  \
    gload_lds16(&A[(m0 + sr + 16) * 1024 + kc_], &As[BUF][(w * 2 + 1) * 512]);  \
  }

  s16x8 bc[4], bn[4];
#pragma unroll
  for (int n = 0; n < 4; ++n) bc[n] = *(const s16x8*)&Bp[n * 16 * 1024];
  STAGE_A(0, 0);
  __syncthreads();

  int cur = 0;
  for (int kt = 0; kt < 32; ++kt) {
    if (kt + 1 < 32) {
      STAGE_A(kt + 1, cur ^ 1);
      const int kn = (kt + 1) * 32;
#pragma unroll
      for (int n = 0; n < 4; ++n) bn[n] = *(const s16x8*)&Bp[n * 16 * 1024 + kn];
    }
    s16x8 af[4];
#pragma unroll
    for (int m = 0; m < 4; ++m)
      af[m] = *(const s16x8*)&As[cur][(wr * 64 + m * 16 + lq) * 32 + lg * 8];
#pragma unroll
    for (int m = 0; m < 4; ++m)
#pragma unroll
      for (int n = 0; n < 4; ++n)
        acc[m][n] = __builtin_amdgcn_mfma_f32_16x16x32_bf16(af[m], bc[n], acc[m][n], 0, 0, 0);
    __syncthreads();
    cur ^= 1;
#pragma unroll
    for (int n = 0; n < 4; ++n) bc[n] = bn[n];
  }
#undef STAGE_A

#pragma unroll
  for (int nf = 0; nf < 4; ++nf) {
    const int ng = n0 + wc * 64 + nf * 16 + lq;
    const float bsv = bo[ng];
#pragma unroll
    for (int mf = 0; mf < 4; ++mf) {
      const int mg = m0 + wr * 64 + mf * 16 + lg * 4;
#pragma unroll
      for (int r = 0; r < 4; ++r)
        out[(mg + r) * 1024 + ng] = acc[mf][nf][r] + bsv;
    }
  }
}

// ---------------- residual + LayerNorm (in-place on d_out), 1 row per block ----------------
__global__ __launch_bounds__(256) void ln_res_kernel(float* __restrict__ out,
                                                     const float* __restrict__ x,
                                                     const float* __restrict__ lnw,
                                                     const float* __restrict__ lnb) {
  const int row = blockIdx.x;
  const int t = threadIdx.x;
  const float4 hv = ((const float4*)(out + row * 1024))[t];
  const float4 xv = ((const float4*)(x + row * 1024))[t];
  const float v0 = hv.x + xv.x, v1 = hv.y + xv.y, v2 = hv.z + xv.z, v3 = hv.w + xv.w;
  float s = v0 + v1 + v2 + v3;
  float s2 = v0 * v0 + v1 * v1 + v2 * v2 + v3 * v3;
#pragma unroll
  for (int o = 32; o > 0; o >>= 1) {
    s += __shfl_down(s, o);
    s2 += __shfl_down(s2, o);
  }
  __shared__ float rs[4], rs2[4];
  const int w = t >> 6;
  if ((t & 63) == 0) { rs[w] = s; rs2[w] = s2; }
  __syncthreads();
  if (t == 0) {
    rs[0] = rs[0] + rs[1] + rs[2] + rs[3];
    rs2[0] = rs2[0] + rs2[1] + rs2[2] + rs2[3];
  }
  __syncthreads();
  const float mean = rs[0] * (1.f / 1024.f);
  const float var = rs2[0] * (1.f / 1024.f) - mean * mean;
  const float rstd = rsqrtf(var + 1e-12f);
  const float4 wv = ((const float4*)lnw)[t];
  const float4 bv = ((const float4*)lnb)[t];
  float4 o;
  o.x = wv.x * ((v0 - mean) * rstd) + bv.x;
  o.y = wv.y * ((v1 - mean) * rstd) + bv.y;
  o.z = wv.z * ((v2 - mean) * rstd) + bv.z;
  o.w = wv.w * ((v3 - mean) * rstd) + bv.w;
  ((float4*)(out + row * 1024))[t] = o;
}

extern "C" void kernel_launch(void* const* d_in, const int* in_sizes, int n_in,
                              void* d_out, int out_size, void* d_ws, size_t ws_size,
                              hipStream_t stream) {
  const float* x = (const float*)d_in[0];
  const int* lens = (const int*)d_in[1];
  const float* Wq = (const float*)d_in[2];
  const float* bq = (const float*)d_in[3];
  const float* Wk = (const float*)d_in[4];
  const float* bk = (const float*)d_in[5];
  const float* Wv = (const float*)d_in[6];
  const float* bv = (const float*)d_in[7];
  const float* Wo = (const float*)d_in[8];
  const float* bo = (const float*)d_in[9];
  const float* lnw = (const float*)d_in[10];
  const float* lnb = (const float*)d_in[11];
  float* out = (float*)d_out;

  char* ws = (char*)d_ws;
  unsigned short* Xbf = (unsigned short*)ws; ws += (size_t)8192 * 1024 * 2;  // also reused as ctx
  unsigned short* Wt  = (unsigned short*)ws; ws += (size_t)4096 * 1024 * 2;
  unsigned short* Qb  = (unsigned short*)ws; ws += (size_t)8192 * 1024 * 2;
  unsigned short* Kb  = (unsigned short*)ws; ws += (size_t)8192 * 1024 * 2;
  unsigned short* VT  = (unsigned short*)ws; ws += (size_t)8192 * 1024 * 2;
  unsigned short* ctx = Xbf;  // Xbf dead after gemm_qkv

  conv_x_kernel<<<8192, 256, 0, stream>>>(x, Xbf);
  pack_w_kernel<<<dim3(32, 32, 4), dim3(32, 8), 0, stream>>>(Wq, Wk, Wv, Wo, Wt);
  gemm_qkv_kernel<<<dim3(24, 64), 256, 0, stream>>>(Xbf, Wt, bq, bk, bv, Qb, Kb, VT);
  attn_kernel<<<2048, 256, 0, stream>>>(Qb, Kb, VT, lens, ctx);
  gemm_o_kernel<<<dim3(8, 64), 256, 0, stream>>>(ctx, Wt + (size_t)3072 * 1024, bo, out);
  ln_res_kernel<<<8192, 256, 0, stream>>>(out, x, lnw, lnb);
}

// Round 9
// 295.696 us; speedup vs baseline: 1.1864x; 1.1864x over previous
//
#include <hip/hip_runtime.h>
#include <hip/hip_bf16.h>
#include <math.h>

// B=8, S=1024, D=1024, H=16, DH=64
typedef __attribute__((ext_vector_type(8))) short s16x8;
typedef __attribute__((ext_vector_type(4))) unsigned short u16x4;
typedef __attribute__((ext_vector_type(4))) float f32x4;

static __device__ __forceinline__ unsigned short f2bf(float f) {
  unsigned int u = __builtin_bit_cast(unsigned int, f);
  u += 0x7fffu + ((u >> 16) & 1u);
  return (unsigned short)(u >> 16);
}

// async global->LDS, 16B per lane; LDS dest = wave-uniform base + lane*16 (m97 pattern)
typedef const __attribute__((address_space(1))) unsigned int* gas1_t;
typedef __attribute__((address_space(3))) unsigned int* las3_t;
static __device__ __forceinline__ void gload_lds16(const unsigned short* g, unsigned short* l) {
  __builtin_amdgcn_global_load_lds((gas1_t)g, (las3_t)l, 16, 0, 0);
}

// ---------------- X fp32 -> bf16 ----------------
__global__ __launch_bounds__(256) void conv_x_kernel(const float* __restrict__ x,
                                                     unsigned short* __restrict__ xb) {
  int i = blockIdx.x * 256 + threadIdx.x;  // grid sized exactly: 8192*1024/4 threads
  const float4 v = ((const float4*)x)[i];
  u16x4 o = {f2bf(v.x), f2bf(v.y), f2bf(v.z), f2bf(v.w)};
  ((u16x4*)xb)[i] = o;
}

// ---------------- pack W^T (bf16): rows [0,1024)=Wq^T, [1024,2048)=Wk^T,
// [2048,3072)=Wv^T, [3072,4096)=Wo^T.  Wt[n][k] = W[k][n] ----------------
__global__ void pack_w_kernel(const float* __restrict__ Wq, const float* __restrict__ Wk,
                              const float* __restrict__ Wv, const float* __restrict__ Wo,
                              unsigned short* __restrict__ Wt) {
  __shared__ float t[32][33];
  const int z = blockIdx.z;
  const float* W = z == 0 ? Wq : (z == 1 ? Wk : (z == 2 ? Wv : Wo));
  const int n0 = blockIdx.x * 32, k0 = blockIdx.y * 32;
  const int tx = threadIdx.x, ty = threadIdx.y;  // 32 x 8
#pragma unroll
  for (int i = 0; i < 4; ++i)
    t[ty + i * 8][tx] = W[(k0 + ty + i * 8) * 1024 + n0 + tx];
  __syncthreads();
#pragma unroll
  for (int i = 0; i < 4; ++i)
    Wt[(z * 1024 + n0 + ty + i * 8) * 1024 + k0 + tx] = f2bf(t[tx][ty + i * 8]);
}

// ---------------- QKV GEMM: [8192x1024] @ [1024x3072] + bias, scatter to
// Q [B][H][S][DH] (scaled log2e/8), K [B][H][S][DH], V^T [B][H][DH][S] ----------------
// 128x128 tile, BK=32, global_load_lds width-16, linear LDS.
// T4 pipeline: 3 LDS buffers, prefetch depth 2, counted s_waitcnt vmcnt(4) + raw
// s_barrier (never vmcnt(0) in steady state) -> each STAGE gets 2 compute phases
// of latency cover instead of 1 (the 2-phase __syncthreads drain limit).
__global__ __launch_bounds__(256, 3) void gemm_qkv_kernel(
    const unsigned short* __restrict__ A, const unsigned short* __restrict__ Wt,
    const float* __restrict__ bq, const float* __restrict__ bk, const float* __restrict__ bv,
    unsigned short* __restrict__ Qb, unsigned short* __restrict__ Kb,
    unsigned short* __restrict__ VT) {
  __shared__ unsigned short As[3][128 * 32];
  __shared__ unsigned short Bs[3][128 * 32];
  const int tid = threadIdx.x;
  const int l = tid & 63, w = tid >> 6;
  const int wr = w >> 1, wc = w & 1;
  const int lq = l & 15, lg = l >> 4;
  const int m0 = blockIdx.y * 128;
  const int n0 = blockIdx.x * 128;  // 24 blocks -> [0,3072)
  const int sr = w * 32 + (l >> 2);   // staging row (call 0); +16 for call 1
  const int sc = (l & 3) * 8;         // staging col (elements)

  f32x4 acc[4][4] = {};

#define STAGE_AB(KT, BUF)                                                          \
  {                                                                                \
    const int kc_ = (KT) * 32 + sc;                                                \
    gload_lds16(&A[(m0 + sr) * 1024 + kc_],       &As[BUF][(w * 2 + 0) * 512]);    \
    gload_lds16(&A[(m0 + sr + 16) * 1024 + kc_],  &As[BUF][(w * 2 + 1) * 512]);    \
    gload_lds16(&Wt[(n0 + sr) * 1024 + kc_],      &Bs[BUF][(w * 2 + 0) * 512]);    \
    gload_lds16(&Wt[(n0 + sr + 16) * 1024 + kc_], &Bs[BUF][(w * 2 + 1) * 512]);    \
  }

  STAGE_AB(0, 0);   // 4 outstanding
  STAGE_AB(1, 1);   // 8 outstanding

  int cb = 0, sb = 2;
  for (int kt = 0; kt < 32; ++kt) {
    // own STAGE(kt) done (leave STAGE(kt+1)'s 4 in flight); last iter drains all
    if (kt < 31) asm volatile("s_waitcnt vmcnt(4)" ::: "memory");
    else         asm volatile("s_waitcnt vmcnt(0)" ::: "memory");
    __builtin_amdgcn_s_barrier();      // all waves: buf[cb] fully staged; compute(kt-1) reads done
    asm volatile("" ::: "memory");     // compiler fence: nothing floats above the barrier
    if (kt + 2 < 32) STAGE_AB(kt + 2, sb);  // overwrites buf last read in compute(kt-1) -> safe
    s16x8 af[4], bf[4];
#pragma unroll
    for (int m = 0; m < 4; ++m)
      af[m] = *(const s16x8*)&As[cb][(wr * 64 + m * 16 + lq) * 32 + lg * 8];
#pragma unroll
    for (int n = 0; n < 4; ++n)
      bf[n] = *(const s16x8*)&Bs[cb][(wc * 64 + n * 16 + lq) * 32 + lg * 8];
#pragma unroll
    for (int m = 0; m < 4; ++m)
#pragma unroll
      for (int n = 0; n < 4; ++n)
        acc[m][n] = __builtin_amdgcn_mfma_f32_16x16x32_bf16(af[m], bf[n], acc[m][n], 0, 0, 0);
    cb = (cb == 2) ? 0 : cb + 1;
    sb = (sb == 2) ? 0 : sb + 1;
  }
#undef STAGE_AB

  const int sec = n0 >> 10;  // uniform per block: 0=Q 1=K 2=V
  const float* bias = sec == 0 ? bq : (sec == 1 ? bk : bv);
#pragma unroll
  for (int nf = 0; nf < 4; ++nf) {
    const int ng = n0 + wc * 64 + nf * 16 + lq;
    const int c = ng & 1023;
    const int h = c >> 6, dh = c & 63;
    const float bsv = bias[c];
#pragma unroll
    for (int mf = 0; mf < 4; ++mf) {
      const int mg = m0 + wr * 64 + mf * 16 + lg * 4;
      const int b = mg >> 10, s = mg & 1023;
#pragma unroll
      for (int r = 0; r < 4; ++r) {
        const float v = acc[mf][nf][r] + bsv;
        if (sec == 0)
          Qb[((b * 16 + h) * 1024 + s + r) * 64 + dh] =
              f2bf(v * (0.125f * 1.44269504088896f));  // fold 1/sqrt(64) and log2(e): softmax in exp2 domain
        else if (sec == 1)
          Kb[((b * 16 + h) * 1024 + s + r) * 64 + dh] = f2bf(v);
        else
          VT[((b * 16 + h) * 64 + dh) * 1024 + s + r] = f2bf(v);
      }
    }
  }
}

// ---------------- flash attention: 1 block = 64 q-rows of one (b,h); 4 waves x 16 rows.
// swapped QK^T (mfma(K,Q)) -> lane owns one q-col; online softmax (exp2 domain);
// PV via ctx^T = V^T @ P^T. K/V tiles staged block-wide in double-buffered LDS via
// global_load_lds (2-phase: issue STAGE(t+1) before compute(t), one barrier per tile).
// XOR chunk-swizzle (chunk ^= row&7) applied on the GLOBAL source + on ds_read addr,
// LDS write stays linear (rule #21): balanced 32B/bank reads.
__global__ __launch_bounds__(256, 3) void attn_kernel(
    const unsigned short* __restrict__ Qb, const unsigned short* __restrict__ Kb,
    const unsigned short* __restrict__ VT, const int* __restrict__ lens,
    unsigned short* __restrict__ ctx) {
  __shared__ unsigned short Ks[2][64 * 64];  // [buf][row*64 + chunk*8], chunk pre-swizzled
  __shared__ unsigned short Vs[2][64 * 64];
  __shared__ unsigned short Pw[4][16][72];   // per-wave P[q][k] tile, padded
  const int tid = threadIdx.x;
  const int l = tid & 63, w = tid >> 6;
  const int lq = l & 15, lg = l >> 4;
  const int l8r = l >> 3;      // staging: row within 8-row group
  const int swz = (l & 7) ^ (l8r & 7);  // source chunk for linear LDS slot
  const int qt = blockIdx.x & 15;
  const int bh = blockIdx.x >> 4;
  const int b = bh >> 4, h = bh & 15;
  const int len = lens[b];

  const unsigned short* Qp = Qb + bh * 1024 * 64;
  const unsigned short* Kp = Kb + bh * 1024 * 64;
  const unsigned short* Vp = VT + bh * 64 * 1024;

  const int qrow = qt * 64 + w * 16 + lq;
  s16x8 qf[2];
  qf[0] = *(const s16x8*)&Qp[qrow * 64 + lg * 8];
  qf[1] = *(const s16x8*)&Qp[qrow * 64 + 32 + lg * 8];

  float mrun = -INFINITY, lrun = 0.f;
  f32x4 cacc[4] = {};

  const int nkt = (len + 63) >> 6;

#define STAGE_KV(KT, BUF)                                                                     \
  {                                                                                           \
    const int kb_ = (KT) * 64;                                                                \
    gload_lds16(&Kp[(kb_ + w * 16 + l8r) * 64 + swz * 8],      &Ks[BUF][(w * 16) * 64]);      \
    gload_lds16(&Kp[(kb_ + w * 16 + 8 + l8r) * 64 + swz * 8],  &Ks[BUF][(w * 16 + 8) * 64]);  \
    gload_lds16(&Vp[(w * 16 + l8r) * 1024 + kb_ + swz * 8],     &Vs[BUF][(w * 16) * 64]);     \
    gload_lds16(&Vp[(w * 16 + 8 + l8r) * 1024 + kb_ + swz * 8], &Vs[BUF][(w * 16 + 8) * 64]); \
  }

  STAGE_KV(0, 0);
  __syncthreads();  // tile 0 staged

  int cur = 0;
  for (int kt = 0; kt < nkt; ++kt) {
    if (kt + 1 < nkt) STAGE_KV(kt + 1, cur ^ 1);  // issue-only; drained at end-of-iter barrier
    const int kbase = kt * 64;
    // scores^T tile [64 k][16 q] from LDS (swizzled read)
    f32x4 sacc[4] = {};
#pragma unroll
    for (int kk = 0; kk < 2; ++kk) {
#pragma unroll
      for (int n = 0; n < 4; ++n) {
        s16x8 kf = *(const s16x8*)&Ks[cur][(n * 16 + lq) * 64 + (((kk * 4 + lg) ^ (lq & 7)) << 3)];
        sacc[n] = __builtin_amdgcn_mfma_f32_16x16x32_bf16(kf, qf[kk], sacc[n], 0, 0, 0);
      }
    }
    // mask + tile max (per q-col: 16 lane-local + xor16 + xor32)
    float sv[4][4];
    float tmax = -INFINITY;
#pragma unroll
    for (int n = 0; n < 4; ++n)
#pragma unroll
      for (int r = 0; r < 4; ++r) {
        const int krow = kbase + n * 16 + lg * 4 + r;
        const float s = (krow < len) ? sacc[n][r] : -INFINITY;
        sv[n][r] = s;
        tmax = fmaxf(tmax, s);
      }
    tmax = fmaxf(tmax, __shfl_xor(tmax, 16));
    tmax = fmaxf(tmax, __shfl_xor(tmax, 32));
    const float mnew = fmaxf(mrun, tmax);
    const float corr = exp2f(mrun - mnew);  // exp2 domain (log2e folded into Q); first tile: 0
    float psum = 0.f;
#pragma unroll
    for (int n = 0; n < 4; ++n) {
      u16x4 pp;
#pragma unroll
      for (int r = 0; r < 4; ++r) {
        const float p = exp2f(sv[n][r] - mnew);  // masked -> exp2(-inf)=0
        psum += p;
        pp[r] = f2bf(p);
      }
      *(u16x4*)&Pw[w][lq][n * 16 + lg * 4] = pp;
    }
    psum += __shfl_xor(psum, 16);
    psum += __shfl_xor(psum, 32);
    lrun = lrun * corr + psum;
    mrun = mnew;
#pragma unroll
    for (int d = 0; d < 4; ++d) cacc[d] *= corr;
    asm volatile("s_waitcnt lgkmcnt(0)" ::: "memory");  // P writes visible to wave's reads
    // ctx^T += V^T @ P^T  (V from LDS, swizzled read)
#pragma unroll
    for (int kk = 0; kk < 2; ++kk) {
      s16x8 pf = *(const s16x8*)&Pw[w][lq][kk * 32 + lg * 8];
#pragma unroll
      for (int d = 0; d < 4; ++d) {
        s16x8 vf = *(const s16x8*)&Vs[cur][(d * 16 + lq) * 64 + (((kk * 4 + lg) ^ (lq & 7)) << 3)];
        cacc[d] = __builtin_amdgcn_mfma_f32_16x16x32_bf16(vf, pf, cacc[d], 0, 0, 0);
      }
    }
    __syncthreads();  // drains vmcnt (prefetch t+1 done) + lgkm; buffers safe to flip
    cur ^= 1;
  }
#undef STAGE_KV

  const float inv = 1.f / lrun;
  unsigned short* cp = ctx + (b * 1024 + qt * 64 + w * 16 + lq) * 1024 + h * 64;
#pragma unroll
  for (int d = 0; d < 4; ++d) {
    u16x4 o;
#pragma unroll
    for (int r = 0; r < 4; ++r) o[r] = f2bf(cacc[d][r] * inv);
    *(u16x4*)&cp[d * 16 + lg * 4] = o;
  }
}

// ---------------- O-proj GEMM: ctx[8192x1024] @ Wo + bo -> fp32 hidden (d_out) ----------------
// same T4 3-buffer counted-vmcnt pipeline as gemm_qkv.
__global__ __launch_bounds__(256, 3) void gemm_o_kernel(const unsigned short* __restrict__ A,
                                                        const unsigned short* __restrict__ Wt,
                                                        const float* __restrict__ bo,
                                                        float* __restrict__ out) {
  __shared__ unsigned short As[3][128 * 32];
  __shared__ unsigned short Bs[3][128 * 32];
  const int tid = threadIdx.x;
  const int l = tid & 63, w = tid >> 6;
  const int wr = w >> 1, wc = w & 1;
  const int lq = l & 15, lg = l >> 4;
  const int m0 = blockIdx.y * 128;
  const int n0 = blockIdx.x * 128;
  const int sr = w * 32 + (l >> 2);
  const int sc = (l & 3) * 8;

  f32x4 acc[4][4] = {};

#define STAGE_AB(KT, BUF)                                                          \
  {                                                                                \
    const int kc_ = (KT) * 32 + sc;                                                \
    gload_lds16(&A[(m0 + sr) * 1024 + kc_],       &As[BUF][(w * 2 + 0) * 512]);    \
    gload_lds16(&A[(m0 + sr + 16) * 1024 + kc_],  &As[BUF][(w * 2 + 1) * 512]);    \
    gload_lds16(&Wt[(n0 + sr) * 1024 + kc_],      &Bs[BUF][(w * 2 + 0) * 512]);    \
    gload_lds16(&Wt[(n0 + sr + 16) * 1024 + kc_], &Bs[BUF][(w * 2 + 1) * 512]);    \
  }

  STAGE_AB(0, 0);
  STAGE_AB(1, 1);

  int cb = 0, sb = 2;
  for (int kt = 0; kt < 32; ++kt) {
    if (kt < 31) asm volatile("s_waitcnt vmcnt(4)" ::: "memory");
    else         asm volatile("s_waitcnt vmcnt(0)" ::: "memory");
    __builtin_amdgcn_s_barrier();
    asm volatile("" ::: "memory");
    if (kt + 2 < 32) STAGE_AB(kt + 2, sb);
    s16x8 af[4], bf[4];
#pragma unroll
    for (int m = 0; m < 4; ++m)
      af[m] = *(const s16x8*)&As[cb][(wr * 64 + m * 16 + lq) * 32 + lg * 8];
#pragma unroll
    for (int n = 0; n < 4; ++n)
      bf[n] = *(const s16x8*)&Bs[cb][(wc * 64 + n * 16 + lq) * 32 + lg * 8];
#pragma unroll
    for (int m = 0; m < 4; ++m)
#pragma unroll
      for (int n = 0; n < 4; ++n)
        acc[m][n] = __builtin_amdgcn_mfma_f32_16x16x32_bf16(af[m], bf[n], acc[m][n], 0, 0, 0);
    cb = (cb == 2) ? 0 : cb + 1;
    sb = (sb == 2) ? 0 : sb + 1;
  }
#undef STAGE_AB

#pragma unroll
  for (int nf = 0; nf < 4; ++nf) {
    const int ng = n0 + wc * 64 + nf * 16 + lq;
    const float bsv = bo[ng];
#pragma unroll
    for (int mf = 0; mf < 4; ++mf) {
      const int mg = m0 + wr * 64 + mf * 16 + lg * 4;
#pragma unroll
      for (int r = 0; r < 4; ++r)
        out[(mg + r) * 1024 + ng] = acc[mf][nf][r] + bsv;
    }
  }
}

// ---------------- residual + LayerNorm (in-place on d_out), 1 row per block ----------------
__global__ __launch_bounds__(256) void ln_res_kernel(float* __restrict__ out,
                                                     const float* __restrict__ x,
                                                     const float* __restrict__ lnw,
                                                     const float* __restrict__ lnb) {
  const int row = blockIdx.x;
  const int t = threadIdx.x;
  const float4 hv = ((const float4*)(out + row * 1024))[t];
  const float4 xv = ((const float4*)(x + row * 1024))[t];
  const float v0 = hv.x + xv.x, v1 = hv.y + xv.y, v2 = hv.z + xv.z, v3 = hv.w + xv.w;
  float s = v0 + v1 + v2 + v3;
  float s2 = v0 * v0 + v1 * v1 + v2 * v2 + v3 * v3;
#pragma unroll
  for (int o = 32; o > 0; o >>= 1) {
    s += __shfl_down(s, o);
    s2 += __shfl_down(s2, o);
  }
  __shared__ float rs[4], rs2[4];
  const int w = t >> 6;
  if ((t & 63) == 0) { rs[w] = s; rs2[w] = s2; }
  __syncthreads();
  if (t == 0) {
    rs[0] = rs[0] + rs[1] + rs[2] + rs[3];
    rs2[0] = rs2[0] + rs2[1] + rs2[2] + rs2[3];
  }
  __syncthreads();
  const float mean = rs[0] * (1.f / 1024.f);
  const float var = rs2[0] * (1.f / 1024.f) - mean * mean;
  const float rstd = rsqrtf(var + 1e-12f);
  const float4 wv = ((const float4*)lnw)[t];
  const float4 bv = ((const float4*)lnb)[t];
  float4 o;
  o.x = wv.x * ((v0 - mean) * rstd) + bv.x;
  o.y = wv.y * ((v1 - mean) * rstd) + bv.y;
  o.z = wv.z * ((v2 - mean) * rstd) + bv.z;
  o.w = wv.w * ((v3 - mean) * rstd) + bv.w;
  ((float4*)(out + row * 1024))[t] = o;
}

extern "C" void kernel_launch(void* const* d_in, const int* in_sizes, int n_in,
                              void* d_out, int out_size, void* d_ws, size_t ws_size,
                              hipStream_t stream) {
  const float* x = (const float*)d_in[0];
  const int* lens = (const int*)d_in[1];
  const float* Wq = (const float*)d_in[2];
  const float* bq = (const float*)d_in[3];
  const float* Wk = (const float*)d_in[4];
  const float* bk = (const float*)d_in[5];
  const float* Wv = (const float*)d_in[6];
  const float* bv = (const float*)d_in[7];
  const float* Wo = (const float*)d_in[8];
  const float* bo = (const float*)d_in[9];
  const float* lnw = (const float*)d_in[10];
  const float* lnb = (const float*)d_in[11];
  float* out = (float*)d_out;

  char* ws = (char*)d_ws;
  unsigned short* Xbf = (unsigned short*)ws; ws += (size_t)8192 * 1024 * 2;  // also reused as ctx
  unsigned short* Wt  = (unsigned short*)ws; ws += (size_t)4096 * 1024 * 2;
  unsigned short* Qb  = (unsigned short*)ws; ws += (size_t)8192 * 1024 * 2;
  unsigned short* Kb  = (unsigned short*)ws; ws += (size_t)8192 * 1024 * 2;
  unsigned short* VT  = (unsigned short*)ws; ws += (size_t)8192 * 1024 * 2;
  unsigned short* ctx = Xbf;  // Xbf dead after gemm_qkv

  conv_x_kernel<<<8192, 256, 0, stream>>>(x, Xbf);
  pack_w_kernel<<<dim3(32, 32, 4), dim3(32, 8), 0, stream>>>(Wq, Wk, Wv, Wo, Wt);
  gemm_qkv_kernel<<<dim3(24, 64), 256, 0, stream>>>(Xbf, Wt, bq, bk, bv, Qb, Kb, VT);
  attn_kernel<<<2048, 256, 0, stream>>>(Qb, Kb, VT, lens, ctx);
  gemm_o_kernel<<<dim3(8, 64), 256, 0, stream>>>(ctx, Wt + (size_t)3072 * 1024, bo, out);
  ln_res_kernel<<<8192, 256, 0, stream>>>(out, x, lnw, lnb);
}